// Round 1
// baseline (2278.188 us; speedup 1.0000x reference)
//
#include <hip/hip_runtime.h>

// RGCN on MI355X: CSR-by-dst built once, then per conv:
//   Phase A: S[n, b*100+d] = sum_{e: dst=n} att[type_e,b]*norm_e*invdeg_n * x[src_e,d]
//   Phase B: out = S @ basis_flat + x @ root + bias  (fp32 vector GEMM, K=1000(+100))
// Layer chain: L0(set1) -> L1(set1,relu) -> L2(set2) -> L3(set1,relu) -> L4(set3)

#define DIMD 100
#define NBASES 10

static inline size_t align256(size_t x) { return (x + 255) & ~(size_t)255; }

// ---------------- preprocessing kernels ----------------

__global__ __launch_bounds__(256) void hist_kernel(const int* __restrict__ dst,
                                                   int* __restrict__ counts, int E) {
    int e = blockIdx.x * 256 + threadIdx.x;
    if (e < E) atomicAdd(&counts[dst[e]], 1);
}

__global__ __launch_bounds__(1024) void scan_kernel(const int* __restrict__ counts,
                                                    int* __restrict__ row_ptr,
                                                    int* __restrict__ next_pos, int n) {
    __shared__ int part[1024];
    __shared__ int base_s[1024];
    int t = threadIdx.x;
    int chunk = (n + 1023) / 1024;
    int lo = t * chunk, hi = min(lo + chunk, n);
    int s = 0;
    for (int i = lo; i < hi; ++i) s += counts[i];
    part[t] = s;
    __syncthreads();
    if (t == 0) {
        int run = 0;
        for (int i = 0; i < 1024; ++i) { int v = part[i]; base_s[i] = run; run += v; }
        row_ptr[n] = run;   // == E
    }
    __syncthreads();
    int run = base_s[t];
    for (int i = lo; i < hi; ++i) {
        row_ptr[i] = run;
        next_pos[i] = run;
        run += counts[i];
    }
}

__global__ __launch_bounds__(256) void scatter_kernel(
        const int* __restrict__ src, const int* __restrict__ dst,
        const int* __restrict__ etype, const float* __restrict__ enorm,
        const int* __restrict__ counts, int* __restrict__ next_pos,
        int* __restrict__ ssrc, int* __restrict__ stype, float* __restrict__ snid, int E) {
    int e = blockIdx.x * 256 + threadIdx.x;
    if (e < E) {
        int d = dst[e];
        int pos = atomicAdd(&next_pos[d], 1);
        ssrc[pos] = src[e];
        stype[pos] = etype[e];
        float deg = (float)max(counts[d], 1);
        snid[pos] = enorm[e] / deg;   // fold mean into per-edge coef
    }
}

__global__ __launch_bounds__(256) void gather_kernel(const int* __restrict__ entity,
                                                     const float* __restrict__ emb,
                                                     float* __restrict__ x, int total) {
    int i = blockIdx.x * 256 + threadIdx.x;
    if (i < total) {
        int n = i / DIMD;
        int d = i - n * DIMD;
        x[i] = emb[(size_t)entity[n] * DIMD + d];
    }
}

// ---------------- Phase A: scatter into S (one wave per node) ----------------

__global__ __launch_bounds__(256) void phaseA_kernel(
        const float* __restrict__ x, const int* __restrict__ row_ptr,
        const int* __restrict__ ssrc, const int* __restrict__ stype,
        const float* __restrict__ snid, const float* __restrict__ att,
        float* __restrict__ S, int N) {
    __shared__ float att_s[1000];   // [R=100][B=10]
    for (int i = threadIdx.x; i < 1000; i += 256) att_s[i] = att[i];
    __syncthreads();

    int wave = threadIdx.x >> 6;
    int l = threadIdx.x & 63;
    int n = blockIdx.x * 4 + wave;
    if (n >= N) return;

    int e0 = row_ptr[n], e1 = row_ptr[n + 1];
    float acc0[NBASES];
    float acc1[NBASES];
#pragma unroll
    for (int b = 0; b < NBASES; ++b) { acc0[b] = 0.f; acc1[b] = 0.f; }
    bool hi = (l < DIMD - 64);   // lanes 0..35 also own d = 64+l

    for (int e = e0; e < e1; ++e) {
        int sidx = ssrc[e];
        int t = stype[e];
        float nv = snid[e];
        const float* xr = x + (size_t)sidx * DIMD;
        float x0 = xr[l];
        float x1 = hi ? xr[64 + l] : 0.f;
        const float* ar = att_s + t * NBASES;
#pragma unroll
        for (int b = 0; b < NBASES; ++b) {
            float c = ar[b] * nv;
            acc0[b] += c * x0;
            acc1[b] += c * x1;
        }
    }
    float* Sr = S + (size_t)n * (NBASES * DIMD);
#pragma unroll
    for (int b = 0; b < NBASES; ++b) {
        Sr[b * DIMD + l] = acc0[b];
        if (hi) Sr[b * DIMD + 64 + l] = acc1[b];
    }
}

// ---------------- Phase B: out = S @ Bm + x @ root + bias ----------------
// TM=128 rows, TN=128 cols (100 valid), KC=20. 256 threads, 8x8 microtile.

__global__ __launch_bounds__(256) void phaseB_kernel(
        const float* __restrict__ S, const float* __restrict__ x,
        const float* __restrict__ Bm,   // [1000][100] = basis viewed flat
        const float* __restrict__ root, // [100][100]
        const float* __restrict__ bias, float* __restrict__ out,
        int N, int do_relu) {
    __shared__ __align__(16) float At[20 * 132];   // [k][row], padded stride 132
    __shared__ __align__(16) float Bt[20 * 144];   // [k][col swizzled], stride 144

    int tid = threadIdx.x;
    int tx = tid & 15, ty = tid >> 4;
    int n0 = blockIdx.x * 128;

    float acc[8][8];
#pragma unroll
    for (int j = 0; j < 8; ++j)
#pragma unroll
        for (int i = 0; i < 8; ++i) acc[j][i] = 0.f;

    for (int phase = 0; phase < 2; ++phase) {
        const float* A = phase ? x : S;
        const float* B = phase ? root : Bm;
        const int K = phase ? 100 : 1000;
        const int astride = phase ? 100 : 1000;

        for (int k0 = 0; k0 < K; k0 += 20) {
            __syncthreads();   // protect LDS from previous iteration's readers
            // stage A-tile transposed: 128 rows x 20 k  (640 float4)
#pragma unroll
            for (int i = 0; i < 3; ++i) {
                int f4 = tid + i * 256;
                if (f4 < 640) {
                    int r = f4 / 5, k4 = f4 % 5;
                    int gr = min(n0 + r, N - 1);
                    const float4 v = *(const float4*)(A + (size_t)gr * astride + k0 + k4 * 4);
                    At[(k4 * 4 + 0) * 132 + r] = v.x;
                    At[(k4 * 4 + 1) * 132 + r] = v.y;
                    At[(k4 * 4 + 2) * 132 + r] = v.z;
                    At[(k4 * 4 + 3) * 132 + r] = v.w;
                }
            }
            // stage B-tile: 20 k x 128 cols, cols >= 100 zero-padded (640 float4)
#pragma unroll
            for (int i = 0; i < 3; ++i) {
                int f4 = tid + i * 256;
                if (f4 < 640) {
                    int k = f4 >> 5, c4 = f4 & 31;
                    float4 v = make_float4(0.f, 0.f, 0.f, 0.f);
                    if (c4 < 25) v = *(const float4*)(B + (size_t)(k0 + k) * 100 + c4 * 4);
                    int phys = c4 * 4 + (c4 >> 3) * 4;   // +4 dwords per 32: breaks 4-way bank conflict
                    *(float4*)&Bt[k * 144 + phys] = v;
                }
            }
            __syncthreads();
#pragma unroll
            for (int k = 0; k < 20; ++k) {
                const float4* ap = (const float4*)&At[k * 132 + ty * 8];
                float4 a0 = ap[0], a1 = ap[1];
                const float4* bp = (const float4*)&Bt[k * 144 + tx * 8 + (tx >> 2) * 4];
                float4 b0 = bp[0], b1 = bp[1];
                float av[8] = {a0.x, a0.y, a0.z, a0.w, a1.x, a1.y, a1.z, a1.w};
                float bv[8] = {b0.x, b0.y, b0.z, b0.w, b1.x, b1.y, b1.z, b1.w};
#pragma unroll
                for (int j = 0; j < 8; ++j)
#pragma unroll
                    for (int i = 0; i < 8; ++i) acc[j][i] += av[j] * bv[i];
            }
        }
    }

    // epilogue: + bias, optional relu, store valid 100 cols
#pragma unroll
    for (int j = 0; j < 8; ++j) {
        int r = n0 + ty * 8 + j;
        if (r < N) {
#pragma unroll
            for (int i = 0; i < 8; ++i) {
                int c = tx * 8 + i;
                if (c < DIMD) {
                    float v = acc[j][i] + bias[c];
                    if (do_relu) v = fmaxf(v, 0.f);
                    out[(size_t)r * DIMD + c] = v;
                }
            }
        }
    }
}

// ---------------- driver ----------------

extern "C" void kernel_launch(void* const* d_in, const int* in_sizes, int n_in,
                              void* d_out, int out_size, void* d_ws, size_t ws_size,
                              hipStream_t stream) {
    const int* entity = (const int*)d_in[0];
    const int* edge_index = (const int*)d_in[1];
    const int* edge_type = (const int*)d_in[2];
    const float* edge_norm = (const float*)d_in[3];
    const float* emb = (const float*)d_in[4];
    const float* basisP[3] = {(const float*)d_in[5], (const float*)d_in[9], (const float*)d_in[13]};
    const float* attP[3]   = {(const float*)d_in[6], (const float*)d_in[10], (const float*)d_in[14]};
    const float* rootP[3]  = {(const float*)d_in[7], (const float*)d_in[11], (const float*)d_in[15]};
    const float* biasP[3]  = {(const float*)d_in[8], (const float*)d_in[12], (const float*)d_in[16]};

    const int N = in_sizes[0];
    const int E = in_sizes[1] / 2;
    const int* src = edge_index;
    const int* dst = edge_index + E;

    // workspace layout
    char* w = (char*)d_ws;
    float* S = (float*)w;            w += align256((size_t)N * NBASES * DIMD * 4);
    float* xA = (float*)w;           w += align256((size_t)N * DIMD * 4);
    float* xB = (float*)w;           w += align256((size_t)N * DIMD * 4);
    int* counts = (int*)w;           w += align256((size_t)N * 4);
    int* row_ptr = (int*)w;          w += align256((size_t)(N + 1) * 4);
    int* next_pos = (int*)w;         w += align256((size_t)N * 4);
    int* ssrc = (int*)w;             w += align256((size_t)E * 4);
    int* stype = (int*)w;            w += align256((size_t)E * 4);
    float* snid = (float*)w;         w += align256((size_t)E * 4);

    // ---- build CSR by dst (shared by all 5 convs) ----
    hipMemsetAsync(counts, 0, (size_t)N * 4, stream);
    int gE = (E + 255) / 256;
    hist_kernel<<<gE, 256, 0, stream>>>(dst, counts, E);
    scan_kernel<<<1, 1024, 0, stream>>>(counts, row_ptr, next_pos, N);
    scatter_kernel<<<gE, 256, 0, stream>>>(src, dst, edge_type, edge_norm, counts,
                                           next_pos, ssrc, stype, snid, E);
    // ---- x0 = emb[entity] ----
    int totalX = N * DIMD;
    gather_kernel<<<(totalX + 255) / 256, 256, 0, stream>>>(entity, emb, xA, totalX);

    // ---- 5 conv layers ----
    const int pidx[5] = {0, 0, 1, 0, 2};
    const int relu[5] = {0, 1, 0, 1, 0};
    float* bufin[5]  = {xA, xB, xA, xB, xA};
    float* bufout[5] = {xB, xA, xB, xA, (float*)d_out};

    int gA = (N + 3) / 4;
    int gB = (N + 127) / 128;
    for (int l = 0; l < 5; ++l) {
        int p = pidx[l];
        phaseA_kernel<<<gA, 256, 0, stream>>>(bufin[l], row_ptr, ssrc, stype, snid,
                                              attP[p], S, N);
        phaseB_kernel<<<gB, 256, 0, stream>>>(S, bufin[l], basisP[p], rootP[p], biasP[p],
                                              bufout[l], N, relu[l]);
    }
}